// Round 11
// baseline (17.366 us; speedup 1.0000x reference)
//
#include <hip/hip_runtime.h>
#include <limits.h>

// BKT: B=4096 students, T=512 timesteps, K=2048 skills.
// R11 = R10 with the two remaining critical-path items removed:
//  1. t/g/s param gathers hoisted to the load phase, issued unconditionally
//     for ALL lanes (R4 proved gather instr count is ~free). Previously they
//     were issued only after the walk proved rank>0 -> ~400-500cy exposed
//     latency, paid by EVERY wave (P(wave has a replaying lane) ~ 1).
//  2. direct-mapped 2048-entry head table (was hashed 1024): no alien hops,
//     no per-hop skill-filter compare; node = [10]=resp bit, [9:0]=prev ptr.
// LDS 10KB -> 8 blocks/CU (32 waves, full TLP). launch_bounds(256,8) pins
// VGPR <= 64 so the 8 in-flight loads can't drop occupancy.

#define BKT_B 4096
#define BKT_T 512
#define BKT_K 2048
#define BLK   256
#define TPT   (BKT_T / BLK)   // 2 timesteps per thread
#define PTR_END 0x3FF

__device__ __forceinline__ float bkt_update(float p, int rbit, float ss,
                                            float gg, float tt) {
  float num, den;
  if (rbit) {                // correct response
    num = p * (1.0f - ss);
    den = num + (1.0f - p) * gg;
  } else {                   // incorrect response
    num = p * ss;
    den = num + (1.0f - p) * (1.0f - gg);
  }
  const float q = num / den; // Bayesian posterior
  return q + (1.0f - q) * tt;// learning transition
}

__global__ __launch_bounds__(BLK, 8) void bkt_kernel(
    const int* __restrict__ skills,
    const float* __restrict__ resp,
    const float* __restrict__ k0,
    const float* __restrict__ tp,
    const float* __restrict__ gp,
    const float* __restrict__ sp,
    float* __restrict__ out) {
  __shared__ int head_s[BKT_K];  // 8KB direct-mapped: last-arrival t, -1 empty
  __shared__ int node_s[BKT_T];  // 2KB packed {resp bit, prev ptr}

  const int b = blockIdx.x;
  const int base = b * BKT_T;
  const int tid = threadIdx.x;

  // load phase: coalesced row loads, then ALL param gathers issued up front
  // so their latency hides under LDS init + build + walk.
  int   sk[TPT];
  float rr[TPT];
#pragma unroll
  for (int u = 0; u < TPT; ++u) {
    const int t = tid + u * BLK;
    sk[u] = skills[base + t];
    rr[u] = resp[base + t];
  }
  float k0v[TPT], ssv[TPT], ggv[TPT], ttv[TPT];
#pragma unroll
  for (int u = 0; u < TPT; ++u) {
    k0v[u] = k0[sk[u]];
    ssv[u] = sp[sk[u]];
    ggv[u] = gp[sk[u]];
    ttv[u] = tp[sk[u]];
  }

  // head init: 2048 ints = two int4 stores per thread
  {
    int4* h4 = (int4*)head_s;
#pragma unroll
    for (int i = 0; i < 2; ++i)
      h4[tid + i * BLK] = make_int4(-1, -1, -1, -1);
  }
  __syncthreads();

  // build per-skill linked lists (arrival order arbitrary)
#pragma unroll
  for (int u = 0; u < TPT; ++u) {
    const int t = tid + u * BLK;
    const int old = atomicExch(&head_s[sk[u]], t);
    const int ptr = (old < 0) ? PTR_END : old;
    node_s[t] = ptr | ((rr[u] > 0.5f ? 1 : 0) << 10);
  }
  __syncthreads();

#pragma unroll
  for (int u = 0; u < TPT; ++u) {
    const int t = tid + u * BLK;
    const int head = head_s[sk[u]];

    // rank walk; capture min j (first replay target) + its node
    int rank = 0, minj = INT_MAX, minnode = 0;
    for (int j = head; j >= 0; ) {
      const int node = node_s[j];
      if (j < t) {
        ++rank;
        if (j < minj) { minj = j; minnode = node; }
      }
      const int nx = node & PTR_END;
      j = (nx == PTR_END) ? -1 : nx;
    }

    float p = k0v[u];                  // first-touch prior (rank-0 answer)

    if (rank > 0) {                    // ~12% of lanes: replay in time order
      const float ss = ssv[u];
      const float gg = ggv[u];
      const float tt = ttv[u];
      p = bkt_update(p, (minnode >> 10) & 1, ss, gg, tt);
      int cur = minj;
      for (int rd = 1; rd < rank; ++rd) {
        int best = INT_MAX, bestnode = 0;
        for (int j = head; j >= 0; ) {
          const int node = node_s[j];
          if (j < t && j > cur && j < best) { best = j; bestnode = node; }
          const int nx = node & PTR_END;
          j = (nx == PTR_END) ? -1 : nx;
        }
        p = bkt_update(p, (bestnode >> 10) & 1, ss, gg, tt);
        cur = best;
      }
    }

    out[base + t] = p;                 // emit pre-update mastery
  }
}

extern "C" void kernel_launch(void* const* d_in, const int* in_sizes, int n_in,
                              void* d_out, int out_size, void* d_ws, size_t ws_size,
                              hipStream_t stream) {
  const int*   skills = (const int*)d_in[0];
  const float* resp   = (const float*)d_in[1];
  const float* k0     = (const float*)d_in[2];
  const float* tp     = (const float*)d_in[3];
  const float* gp     = (const float*)d_in[4];
  const float* sp     = (const float*)d_in[5];
  float* out = (float*)d_out;

  bkt_kernel<<<BKT_B, BLK, 0, stream>>>(skills, resp, k0, tp, gp, sp, out);
}